// Round 4
// baseline (274.196 us; speedup 1.0000x reference)
//
#include <hip/hip_runtime.h>
#include <hip/hip_bf16.h>

#define M_Q 50000
#define N_S 50000
#define H_N 32
#define K_P 15
#define C_IN 128
#define C_OUT 128
#define QB 32      // queries per block
#define CAP 96     // staged feature-row slots (mean ~62 active, 4.4 sigma headroom; overflow -> global path)
#define FP 136     // padded feat row stride in bf16 elems (272B = 68 words -> spreads banks)

typedef __attribute__((ext_vector_type(8))) short s8v;      // 8 bf16 = MFMA A/B frag
typedef __attribute__((ext_vector_type(4))) float f4v;      // MFMA C/D frag
typedef __attribute__((ext_vector_type(4))) float fl4;
typedef __attribute__((ext_vector_type(4))) unsigned u4v;

union AF { u4v u; s8v s; };

static __device__ __forceinline__ unsigned f2bf_bits(float x) {
    union { float f; unsigned u; } v; v.f = x;
    return (v.u + 0x7fffu + ((v.u >> 16) & 1u)) >> 16;
}
static __device__ __forceinline__ unsigned pack_bf16(float a, float b) {
    return f2bf_bits(a) | (f2bf_bits(b) << 16);
}
static __device__ __forceinline__ float bf_lo(unsigned u) {
    union { unsigned u; float f; } v; v.u = u << 16; return v.f;
}
static __device__ __forceinline__ float bf_hi(unsigned u) {
    union { unsigned u; float f; } v; v.u = u & 0xffff0000u; return v.f;
}

// ---- pre-pass: W[k][c][d] fp32 -> Wt[k][d][c] bf16 ----
__global__ __launch_bounds__(256) void wcvt_kernel(const float* __restrict__ W,
                                                   unsigned short* __restrict__ Wt) {
    int i = blockIdx.x * 256 + threadIdx.x;
    if (i >= K_P * C_IN * C_OUT) return;
    int c = i & 127, d = (i >> 7) & 127, k = i >> 14;
    Wt[i] = (unsigned short)f2bf_bits(W[((size_t)k * 128 + c) * 128 + d]);
}

// ---- fused main: gather-once, one staging barrier, barrier-free k-loop ----
template <typename IT>
__global__ __launch_bounds__(256, 3) void kpconv_v4(
    const float* __restrict__ q_pts,
    const float* __restrict__ s_pts,
    const float* __restrict__ s_feats,
    const IT* __restrict__ inds,
    const float* __restrict__ kernel_points,
    const unsigned short* __restrict__ Wt,   // bf16 bits, [K][D][C]
    float* __restrict__ out)
{
    __shared__ float s_kp[K_P * 3];
    __shared__ float s_q[QB * 3];
    __shared__ float s_r[QB][H_N][3];               // neighbor - query rel pos
    __shared__ int s_idx[QB][H_N];                  // support index (for overflow path)
    __shared__ unsigned s_hm[K_P][QB];              // per-(k,q) active-h bitmask
    __shared__ unsigned s_kact[K_P][2];             // per-(k,row-half) any-active
    __shared__ unsigned s_anyh[QB];                 // per-q: h active for ANY k
    __shared__ int s_base[QB + 1];                  // exclusive prefix of popcounts
    __shared__ int s_rowidx[CAP];                   // slot -> support index
    __shared__ short s_slot[QB][H_N];               // (q,h) -> slot / -1 / -2
    __shared__ __align__(16) unsigned short s_feat[CAP][FP];  // staged rows, bf16

    const int t = threadIdx.x;
    const int lane = t & 63;
    const int qbase = blockIdx.x * QB;

    if (t < K_P * 3) s_kp[t] = kernel_points[t];
    if (t < QB * 3) {
        int g = qbase * 3 + t;
        s_q[t] = (g < M_Q * 3) ? q_pts[g] : 0.0f;
    }
    __syncthreads();   // barrier 1

    // ---- phase 1: geometry + ballot-built bitmasks (no sqrt, no atomics) ----
    #pragma unroll
    for (int it = 0; it < 4; ++it) {
        const int task = it * 256 + t;
        const int q = task >> 5, h = task & 31;
        const int qg = qbase + q;
        float rx = 1.0e6f, ry = 1.0e6f, rz = 1.0e6f;
        int i32 = 0;
        if (qg < M_Q) {
            long long idx = (long long)inds[(size_t)qg * H_N + h];
            if ((unsigned long long)idx < (unsigned long long)N_S) {
                i32 = (int)idx;
                rx = s_pts[i32 * 3 + 0] - s_q[q * 3 + 0];
                ry = s_pts[i32 * 3 + 1] - s_q[q * 3 + 1];
                rz = s_pts[i32 * 3 + 2] - s_q[q * 3 + 2];
            }
        }
        s_idx[q][h] = i32;
        s_r[q][h][0] = rx; s_r[q][h][1] = ry; s_r[q][h][2] = rz;
        unsigned kmask = 0u;
        #pragma unroll
        for (int k = 0; k < K_P; ++k) {
            const float dx = rx - s_kp[k * 3 + 0];
            const float dy = ry - s_kp[k * 3 + 1];
            const float dz = rz - s_kp[k * 3 + 2];
            const float d2 = dx * dx + dy * dy + dz * dz;
            const bool act = d2 < 1.0f;   // w>0  <=>  d2<1 (exact)
            unsigned long long b = __ballot(act);
            if (lane == 0)       s_hm[k][q] = (unsigned)b;
            else if (lane == 32) s_hm[k][q] = (unsigned)(b >> 32);
            if (act) kmask |= 1u << k;
        }
        unsigned long long ba = __ballot(kmask != 0u);
        if (lane == 0)       s_anyh[q] = (unsigned)ba;
        else if (lane == 32) s_anyh[q] = (unsigned)(ba >> 32);
    }
    __syncthreads();   // barrier 2

    // prefix sum (serial, trivial) + per-(k,half) activity
    if (t == 0) {
        int s = 0;
        #pragma unroll
        for (int q = 0; q < QB; ++q) { s_base[q] = s; s += __popc(s_anyh[q]); }
        s_base[QB] = s;
    }
    if (t < K_P * 2) {
        const int k = t >> 1, half = t & 1;
        unsigned o = 0u;
        #pragma unroll
        for (int i = 0; i < 16; ++i) o |= s_hm[k][half * 16 + i];
        s_kact[k][half] = o;
    }
    __syncthreads();   // barrier 3

    // slot assignment
    #pragma unroll
    for (int it = 0; it < 4; ++it) {
        const int task = it * 256 + t;
        const int q = task >> 5, h = task & 31;
        const unsigned am = s_anyh[q];
        short sl = -1;
        if (am & (1u << h)) {
            const int slot = s_base[q] + __popc(am & ((1u << h) - 1u));
            if (slot < CAP) { sl = (short)slot; s_rowidx[slot] = s_idx[q][h]; }
            else sl = -2;
        }
        s_slot[q][h] = sl;
    }
    __syncthreads();   // barrier 4

    // ---- stage active feature rows to LDS (parallel gathers, once) ----
    {
        const int total = min(s_base[QB], CAP);
        const int c0 = (t & 7) * 16;
        for (int r0 = (t >> 3); r0 < total; r0 += 32) {
            const float* fr = s_feats + (size_t)s_rowidx[r0] * C_IN + c0;
            unsigned* dst = (unsigned*)&s_feat[r0][c0];
            #pragma unroll
            for (int j = 0; j < 4; ++j) {
                const fl4 f = ((const fl4*)fr)[j];
                dst[j * 2 + 0] = pack_bf16(f.x, f.y);
                dst[j * 2 + 1] = pack_bf16(f.z, f.w);
            }
        }
    }
    __syncthreads();   // barrier 5 — LAST barrier; k-loop below is barrier-free

    // ---- k-loop: per-wave independent A-build (registers) + MFMA ----
    const int w2 = t >> 6;
    const int rw = (w2 >> 1) * 16, cw = (w2 & 1) * 64;   // wave tile: 16 rows x 64 cols
    const int quad = lane >> 4, l15 = lane & 15;
    const int q = rw + l15;          // this lane's A row
    const int rhalf = w2 >> 1;

    const f4v zf = {0.0f, 0.0f, 0.0f, 0.0f};
    f4v acc[4]; acc[0] = zf; acc[1] = zf; acc[2] = zf; acc[3] = zf;

    for (int k = 0; k < K_P; ++k) {
        if (s_kact[k][rhalf] == 0u) continue;

        AF af[4];
        #pragma unroll
        for (int kk = 0; kk < 4; ++kk) af[kk].u = (u4v){0u, 0u, 0u, 0u};

        unsigned hm = s_hm[k][q];
        if (hm) {
            float vacc[4][8];
            #pragma unroll
            for (int kk = 0; kk < 4; ++kk)
                #pragma unroll
                for (int j = 0; j < 8; ++j) vacc[kk][j] = 0.0f;
            const float kx = s_kp[k * 3 + 0], ky = s_kp[k * 3 + 1], kz = s_kp[k * 3 + 2];
            do {
                const int h = __builtin_ctz(hm); hm &= hm - 1u;
                const float dx = s_r[q][h][0] - kx;
                const float dy = s_r[q][h][1] - ky;
                const float dz = s_r[q][h][2] - kz;
                const float w = 1.0f - sqrtf(dx * dx + dy * dy + dz * dz);
                const int slot = s_slot[q][h];
                if (slot >= 0) {
                    const unsigned* fr = (const unsigned*)&s_feat[slot][0] + quad * 4;
                    #pragma unroll
                    for (int kk = 0; kk < 4; ++kk) {
                        const u4v d = *(const u4v*)(fr + kk * 16);
                        #pragma unroll
                        for (int j2 = 0; j2 < 4; ++j2) {
                            vacc[kk][2 * j2 + 0] = fmaf(w, bf_lo(d[j2]), vacc[kk][2 * j2 + 0]);
                            vacc[kk][2 * j2 + 1] = fmaf(w, bf_hi(d[j2]), vacc[kk][2 * j2 + 1]);
                        }
                    }
                } else {   // rare overflow: gather fp32 directly
                    const float* fg = s_feats + (size_t)s_idx[q][h] * C_IN + quad * 8;
                    #pragma unroll
                    for (int kk = 0; kk < 4; ++kk) {
                        const fl4 f0 = *(const fl4*)(fg + kk * 32);
                        const fl4 f1 = *(const fl4*)(fg + kk * 32 + 4);
                        vacc[kk][0] = fmaf(w, f0.x, vacc[kk][0]);
                        vacc[kk][1] = fmaf(w, f0.y, vacc[kk][1]);
                        vacc[kk][2] = fmaf(w, f0.z, vacc[kk][2]);
                        vacc[kk][3] = fmaf(w, f0.w, vacc[kk][3]);
                        vacc[kk][4] = fmaf(w, f1.x, vacc[kk][4]);
                        vacc[kk][5] = fmaf(w, f1.y, vacc[kk][5]);
                        vacc[kk][6] = fmaf(w, f1.z, vacc[kk][6]);
                        vacc[kk][7] = fmaf(w, f1.w, vacc[kk][7]);
                    }
                }
            } while (hm);
            #pragma unroll
            for (int kk = 0; kk < 4; ++kk) {
                af[kk].u[0] = pack_bf16(vacc[kk][0], vacc[kk][1]);
                af[kk].u[1] = pack_bf16(vacc[kk][2], vacc[kk][3]);
                af[kk].u[2] = pack_bf16(vacc[kk][4], vacc[kk][5]);
                af[kk].u[3] = pack_bf16(vacc[kk][6], vacc[kk][7]);
            }
        }

        const unsigned short* Wk = Wt + (size_t)k * C_IN * C_OUT;
        #pragma unroll
        for (int ct = 0; ct < 4; ++ct) {
            const unsigned short* wd = Wk + (size_t)(cw + ct * 16 + l15) * C_IN + quad * 8;
            #pragma unroll
            for (int kk = 0; kk < 4; ++kk) {
                const s8v b = *(const s8v*)(wd + kk * 32);
                acc[ct] = __builtin_amdgcn_mfma_f32_16x16x32_bf16(af[kk].s, b, acc[ct], 0, 0, 0);
            }
        }
    }

    // ---- epilogue: C/D layout col=lane&15, row=quad*4+reg ----
    #pragma unroll
    for (int ct = 0; ct < 4; ++ct) {
        #pragma unroll
        for (int r = 0; r < 4; ++r) {
            const int qg = qbase + rw + quad * 4 + r;
            if (qg < M_Q)
                out[(size_t)qg * C_OUT + cw + ct * 16 + l15] = acc[ct][r];
        }
    }
}

extern "C" void kernel_launch(void* const* d_in, const int* in_sizes, int n_in,
                              void* d_out, int out_size, void* d_ws, size_t ws_size,
                              hipStream_t stream) {
    const float* q_pts         = (const float*)d_in[0];
    const float* s_pts         = (const float*)d_in[1];
    const float* s_feats       = (const float*)d_in[2];
    const float* kernel_points = (const float*)d_in[4];
    const float* weights       = (const float*)d_in[5];
    float* out = (float*)d_out;
    const bool i64 = (in_sizes[3] == 2 * M_Q * H_N);

    unsigned short* Wt = (unsigned short*)d_ws;
    wcvt_kernel<<<(K_P * C_IN * C_OUT + 255) / 256, 256, 0, stream>>>(weights, Wt);

    dim3 grid((M_Q + QB - 1) / QB), block(256);
    if (i64)
        kpconv_v4<long long><<<grid, block, 0, stream>>>(
            q_pts, s_pts, s_feats, (const long long*)d_in[3], kernel_points, Wt, out);
    else
        kpconv_v4<int><<<grid, block, 0, stream>>>(
            q_pts, s_pts, s_feats, (const int*)d_in[3], kernel_points, Wt, out);
}

// Round 5
// 232.815 us; speedup vs baseline: 1.1777x; 1.1777x over previous
//
#include <hip/hip_runtime.h>

#define M_Q 50000
#define N_S 50000
#define H_N 32
#define K_P 15
#define C_IN 128
#define C_OUT 128
#define QB 64      // queries per block
#define NT 512     // threads per block (8 waves)
#define EMAX 24    // LDS entry-list capacity per query (mean ~1.9, P(>24) ~ 0)
#define EREG 8     // entries preloaded into registers (tail read from LDS, rare)
#define BP 136     // padded B row stride in bf16 elems (272B -> balanced LDS bank groups)

typedef __attribute__((ext_vector_type(8))) short s8v;      // 8 bf16 = MFMA A/B frag
typedef __attribute__((ext_vector_type(4))) float f4v;      // MFMA C/D frag
typedef __attribute__((ext_vector_type(4))) float fl4;
typedef __attribute__((ext_vector_type(4))) unsigned u4v;

union AF { u4v u; s8v s; };

static __device__ __forceinline__ unsigned f2bf_bits(float x) {
    union { float f; unsigned u; } v; v.f = x;
    return (v.u + 0x7fffu + ((v.u >> 16) & 1u)) >> 16;
}
static __device__ __forceinline__ unsigned pack_bf16(float a, float b) {
    return f2bf_bits(a) | (f2bf_bits(b) << 16);
}

// ---- pre-pass: W[k][c][d] fp32 -> Wt[k][d][c] bf16 ----
__global__ __launch_bounds__(256) void wcvt_kernel(const float* __restrict__ W,
                                                   unsigned short* __restrict__ Wt) {
    int i = blockIdx.x * 256 + threadIdx.x;
    if (i >= K_P * C_IN * C_OUT) return;
    int c = i & 127, d = (i >> 7) & 127, k = i >> 14;
    Wt[i] = (unsigned short)f2bf_bits(W[((size_t)k * 128 + c) * 128 + d]);
}

// ---- main: QB=64 queries/block; entry-list A-build; W_k staged in LDS per k ----
template <typename IT>
__global__ __launch_bounds__(NT, 4) void kpconv_v5(
    const float* __restrict__ q_pts,
    const float* __restrict__ s_pts,
    const float* __restrict__ s_feats,
    const IT* __restrict__ inds,
    const float* __restrict__ kernel_points,
    const unsigned short* __restrict__ Wt,   // bf16 bits, [K][D][C]
    float* __restrict__ out)
{
    __shared__ unsigned short s_B[C_OUT][BP];   // W_k tile: row=d, c along row
    __shared__ float s_ew[QB][EMAX];            // entry weights
    __shared__ unsigned s_em[QB][EMAX];         // entry meta: (k<<16)|idx
    __shared__ int s_cnt[QB];
    __shared__ float s_kp[K_P * 3];
    __shared__ float s_q[QB * 3];

    const int t = threadIdx.x;
    const int lane = t & 63;
    const int w = t >> 6;
    const int quad = lane >> 4, l15 = lane & 15;
    const int qbase = blockIdx.x * QB;

    if (t < K_P * 3) s_kp[t] = kernel_points[t];
    if (t < QB) s_cnt[t] = 0;
    if (t < QB * 3) {
        int g = qbase * 3 + t;
        s_q[t] = (g < M_Q * 3) ? q_pts[g] : 0.0f;
    }
    __syncthreads();

    // ---- phase 1: geometry -> compact per-q entry lists (k, w, idx) ----
    #pragma unroll
    for (int it = 0; it < 4; ++it) {
        const int task = it * NT + t;            // 2048 tasks = 64q x 32h
        const int q = task >> 5, h = task & 31;
        const int qg = qbase + q;
        if (qg < M_Q) {
            long long idx = (long long)inds[(size_t)qg * H_N + h];
            if ((unsigned long long)idx < (unsigned long long)N_S) {
                const int i32 = (int)idx;
                const float rx = s_pts[i32 * 3 + 0] - s_q[q * 3 + 0];
                const float ry = s_pts[i32 * 3 + 1] - s_q[q * 3 + 1];
                const float rz = s_pts[i32 * 3 + 2] - s_q[q * 3 + 2];
                #pragma unroll
                for (int k = 0; k < K_P; ++k) {
                    const float dx = rx - s_kp[k * 3 + 0];
                    const float dy = ry - s_kp[k * 3 + 1];
                    const float dz = rz - s_kp[k * 3 + 2];
                    const float d2 = dx * dx + dy * dy + dz * dz;
                    if (d2 < 1.0f) {             // w>0 <=> d2<1 (exact zero-skip)
                        const float wgt = 1.0f - sqrtf(d2);
                        const int pos = atomicAdd(&s_cnt[q], 1);
                        if (pos < EMAX) {
                            s_ew[q][pos] = wgt;
                            s_em[q][pos] = ((unsigned)k << 16) | (unsigned)i32;
                        }
                    }
                }
            }
        }
    }
    __syncthreads();

    // ---- preload this lane's entry list into registers ----
    const int q = (w & 3) * 16 + l15;       // A row owned by this lane
    const int cw = (w >> 2) * 64;           // output-col base for this wave
    const int cnt = min(s_cnt[q], EMAX);
    float ew[EREG]; unsigned em[EREG];
    unsigned km = 0u;
    #pragma unroll
    for (int i = 0; i < EREG; ++i) {
        ew[i] = 0.0f; em[i] = 0xffff0000u;
        if (i < cnt) {
            ew[i] = s_ew[q][i]; em[i] = s_em[q][i];
            km |= 1u << (em[i] >> 16);
        }
    }
    for (int i = EREG; i < cnt; ++i) km |= 1u << (s_em[q][i] >> 16);

    const f4v zf = {0.0f, 0.0f, 0.0f, 0.0f};
    f4v acc[4]; acc[0] = zf; acc[1] = zf; acc[2] = zf; acc[3] = zf;

    for (int k = 0; k < K_P; ++k) {
        // ---- issue W_k global loads (coalesced; latency overlaps A-build) ----
        const int bd = t >> 2, bc = (t & 3) * 32;     // 128 rows x 4 chunks of 32 elems
        const u4v* bsrc = (const u4v*)(Wt + ((size_t)k * C_OUT + bd) * C_IN + bc);
        const u4v r0 = bsrc[0], r1 = bsrc[1], r2 = bsrc[2], r3 = bsrc[3];

        // ---- A-build for k (registers; ~0.13 gathers per lane) ----
        const bool lact = (km >> k) & 1u;
        const unsigned long long wany = __ballot(lact);
        AF af[4];
        #pragma unroll
        for (int kk = 0; kk < 4; ++kk) af[kk].u = (u4v){0u, 0u, 0u, 0u};
        if (lact) {
            float vacc[4][8];
            #pragma unroll
            for (int kk = 0; kk < 4; ++kk)
                #pragma unroll
                for (int j = 0; j < 8; ++j) vacc[kk][j] = 0.0f;
            #pragma unroll
            for (int i = 0; i < EREG; ++i) {
                if (i < cnt && (int)(em[i] >> 16) == k) {
                    const float wgt = ew[i];
                    const float* fr = s_feats + (size_t)(em[i] & 0xffffu) * C_IN + quad * 8;
                    #pragma unroll
                    for (int kk = 0; kk < 4; ++kk) {
                        const fl4 f0 = *(const fl4*)(fr + kk * 32);
                        const fl4 f1 = *(const fl4*)(fr + kk * 32 + 4);
                        vacc[kk][0] = fmaf(wgt, f0.x, vacc[kk][0]);
                        vacc[kk][1] = fmaf(wgt, f0.y, vacc[kk][1]);
                        vacc[kk][2] = fmaf(wgt, f0.z, vacc[kk][2]);
                        vacc[kk][3] = fmaf(wgt, f0.w, vacc[kk][3]);
                        vacc[kk][4] = fmaf(wgt, f1.x, vacc[kk][4]);
                        vacc[kk][5] = fmaf(wgt, f1.y, vacc[kk][5]);
                        vacc[kk][6] = fmaf(wgt, f1.z, vacc[kk][6]);
                        vacc[kk][7] = fmaf(wgt, f1.w, vacc[kk][7]);
                    }
                }
            }
            for (int i = EREG; i < cnt; ++i) {        // rare LDS tail
                const unsigned meta = s_em[q][i];
                if ((int)(meta >> 16) == k) {
                    const float wgt = s_ew[q][i];
                    const float* fr = s_feats + (size_t)(meta & 0xffffu) * C_IN + quad * 8;
                    #pragma unroll
                    for (int kk = 0; kk < 4; ++kk) {
                        const fl4 f0 = *(const fl4*)(fr + kk * 32);
                        const fl4 f1 = *(const fl4*)(fr + kk * 32 + 4);
                        vacc[kk][0] = fmaf(wgt, f0.x, vacc[kk][0]);
                        vacc[kk][1] = fmaf(wgt, f0.y, vacc[kk][1]);
                        vacc[kk][2] = fmaf(wgt, f0.z, vacc[kk][2]);
                        vacc[kk][3] = fmaf(wgt, f0.w, vacc[kk][3]);
                        vacc[kk][4] = fmaf(wgt, f1.x, vacc[kk][4]);
                        vacc[kk][5] = fmaf(wgt, f1.y, vacc[kk][5]);
                        vacc[kk][6] = fmaf(wgt, f1.z, vacc[kk][6]);
                        vacc[kk][7] = fmaf(wgt, f1.w, vacc[kk][7]);
                    }
                }
            }
            #pragma unroll
            for (int kk = 0; kk < 4; ++kk) {
                af[kk].u[0] = pack_bf16(vacc[kk][0], vacc[kk][1]);
                af[kk].u[1] = pack_bf16(vacc[kk][2], vacc[kk][3]);
                af[kk].u[2] = pack_bf16(vacc[kk][4], vacc[kk][5]);
                af[kk].u[3] = pack_bf16(vacc[kk][6], vacc[kk][7]);
            }
        }

        // ---- commit W_k to LDS; barrier; MFMA from LDS ----
        {
            u4v* bdst = (u4v*)&s_B[bd][bc];
            bdst[0] = r0; bdst[1] = r1; bdst[2] = r2; bdst[3] = r3;
        }
        __syncthreads();   // B ready

        if (wany) {
            #pragma unroll
            for (int ct = 0; ct < 4; ++ct) {
                const int d = cw + ct * 16 + l15;
                #pragma unroll
                for (int kk = 0; kk < 4; ++kk) {
                    const s8v b = *(const s8v*)&s_B[d][kk * 32 + quad * 8];
                    acc[ct] = __builtin_amdgcn_mfma_f32_16x16x32_bf16(af[kk].s, b, acc[ct], 0, 0, 0);
                }
            }
        }
        __syncthreads();   // all B reads done before next k overwrites s_B
    }

    // ---- epilogue: C/D layout col=lane&15, row=quad*4+reg ----
    #pragma unroll
    for (int ct = 0; ct < 4; ++ct) {
        #pragma unroll
        for (int r = 0; r < 4; ++r) {
            const int qg = qbase + (w & 3) * 16 + quad * 4 + r;
            if (qg < M_Q)
                out[(size_t)qg * C_OUT + cw + ct * 16 + l15] = acc[ct][r];
        }
    }
}

extern "C" void kernel_launch(void* const* d_in, const int* in_sizes, int n_in,
                              void* d_out, int out_size, void* d_ws, size_t ws_size,
                              hipStream_t stream) {
    const float* q_pts         = (const float*)d_in[0];
    const float* s_pts         = (const float*)d_in[1];
    const float* s_feats       = (const float*)d_in[2];
    const float* kernel_points = (const float*)d_in[4];
    const float* weights       = (const float*)d_in[5];
    float* out = (float*)d_out;
    const bool i64 = (in_sizes[3] == 2 * M_Q * H_N);

    unsigned short* Wt = (unsigned short*)d_ws;
    wcvt_kernel<<<(K_P * C_IN * C_OUT + 255) / 256, 256, 0, stream>>>(weights, Wt);

    dim3 grid((M_Q + QB - 1) / QB), block(NT);
    if (i64)
        kpconv_v5<long long><<<grid, block, 0, stream>>>(
            q_pts, s_pts, s_feats, (const long long*)d_in[3], kernel_points, Wt, out);
    else
        kpconv_v5<int><<<grid, block, 0, stream>>>(
            q_pts, s_pts, s_feats, (const int*)d_in[3], kernel_points, Wt, out);
}

// Round 6
// 183.920 us; speedup vs baseline: 1.4908x; 1.2658x over previous
//
#include <hip/hip_runtime.h>

#define M_Q 50000
#define N_S 50000
#define H_N 32
#define K_P 15
#define C_IN 128
#define C_OUT 128
#define QB 64      // queries per block
#define NT 512     // threads per block (8 waves)
#define EMAX 24    // per-query entry capacity (mean ~2, P(>24) ~ 0)

typedef __attribute__((ext_vector_type(8))) short s8v;      // 8 bf16 = MFMA A/B frag
typedef __attribute__((ext_vector_type(4))) float f4v;      // MFMA C/D frag
typedef __attribute__((ext_vector_type(4))) float fl4;
typedef __attribute__((ext_vector_type(4))) unsigned u4v;

union AF { u4v u; s8v s; };

static __device__ __forceinline__ unsigned f2bf_bits(float x) {
    union { float f; unsigned u; } v; v.f = x;
    return (v.u + 0x7fffu + ((v.u >> 16) & 1u)) >> 16;
}
static __device__ __forceinline__ unsigned pack_bf16(float a, float b) {
    return f2bf_bits(a) | (f2bf_bits(b) << 16);
}

// ---- pre-pass: W[k][c][d] fp32 -> fragment-major bf16 ----
// slot i = (((k*2+cw)*4+ct)*4+kk)*64+lane ; elems j=0..7
// element (c,d): d = cw*64+ct*16+(lane&15), c = kk*32+(lane>>4)*8+j
__global__ __launch_bounds__(256) void wcvt_frag(const float* __restrict__ W,
                                                 unsigned short* __restrict__ Wtf) {
    int i = blockIdx.x * 256 + threadIdx.x;
    if (i >= K_P * 2 * 4 * 4 * 64) return;
    const int lane = i & 63;
    int r = i >> 6;
    const int kk = r & 3; r >>= 2;
    const int ct = r & 3; r >>= 2;
    const int cw = r & 1;
    const int k  = r >> 1;
    const int d  = cw * 64 + ct * 16 + (lane & 15);
    const int c0 = kk * 32 + (lane >> 4) * 8;
    unsigned short* dst = Wtf + (size_t)i * 8;
    #pragma unroll
    for (int j = 0; j < 8; ++j)
        dst[j] = (unsigned short)f2bf_bits(W[((size_t)k * 128 + c0 + j) * 128 + d]);
}

// ---- main: sorted entry-list pointer-walk + frag-major LDS B staging ----
template <typename IT>
__global__ __launch_bounds__(NT, 4) void kpconv_v6(
    const float* __restrict__ q_pts,
    const float* __restrict__ s_pts,
    const float* __restrict__ s_feats,
    const IT* __restrict__ inds,
    const float* __restrict__ kernel_points,
    const unsigned short* __restrict__ Wtf,  // frag-major bf16
    float* __restrict__ out)
{
    __shared__ unsigned short s_B[2 * 4 * 4 * 64 * 8];  // 32 KB: one k's frags
    __shared__ float s_ew[QB][EMAX];                    // entry weights
    __shared__ unsigned s_em[QB][EMAX];                 // (k<<16)|idx, sorted by k
    __shared__ int s_cnt[QB];
    __shared__ float s_kp[K_P * 3];
    __shared__ float s_q[QB * 3];

    const int t = threadIdx.x;
    const int lane = t & 63;
    const int w = t >> 6;
    const int quad = lane >> 4, l15 = lane & 15;
    const int qbase = blockIdx.x * QB;

    if (t < K_P * 3) s_kp[t] = kernel_points[t];
    if (t < QB) s_cnt[t] = 0;
    if (t < QB * 3) {
        int g = qbase * 3 + t;
        s_q[t] = (g < M_Q * 3) ? q_pts[g] : 0.0f;
    }
    __syncthreads();

    // ---- phase 1: geometry -> unsorted per-q entry lists ----
    #pragma unroll
    for (int it = 0; it < 4; ++it) {
        const int task = it * NT + t;            // 2048 = 64q x 32h
        const int q = task >> 5, h = task & 31;
        const int qg = qbase + q;
        if (qg < M_Q) {
            long long idx = (long long)inds[(size_t)qg * H_N + h];
            if ((unsigned long long)idx < (unsigned long long)N_S) {
                const int i32 = (int)idx;
                const float rx = s_pts[i32 * 3 + 0] - s_q[q * 3 + 0];
                const float ry = s_pts[i32 * 3 + 1] - s_q[q * 3 + 1];
                const float rz = s_pts[i32 * 3 + 2] - s_q[q * 3 + 2];
                #pragma unroll
                for (int k = 0; k < K_P; ++k) {
                    const float dx = rx - s_kp[k * 3 + 0];
                    const float dy = ry - s_kp[k * 3 + 1];
                    const float dz = rz - s_kp[k * 3 + 2];
                    const float d2 = dx * dx + dy * dy + dz * dz;
                    if (d2 < 1.0f) {             // w>0 <=> d2<1 (exact zero-skip)
                        const float wgt = 1.0f - sqrtf(d2);
                        const int pos = atomicAdd(&s_cnt[q], 1);
                        if (pos < EMAX) {
                            s_ew[q][pos] = wgt;
                            s_em[q][pos] = ((unsigned)k << 16) | (unsigned)i32;
                        }
                    }
                }
            }
        }
    }
    __syncthreads();

    // ---- sort each query's list by k (tiny insertion sort) ----
    if (t < QB) {
        const int n = min(s_cnt[t], EMAX);
        s_cnt[t] = n;
        for (int i = 1; i < n; ++i) {
            const unsigned mi = s_em[t][i];
            const float wi = s_ew[t][i];
            int j = i - 1;
            while (j >= 0 && s_em[t][j] > mi) {
                s_em[t][j + 1] = s_em[t][j];
                s_ew[t][j + 1] = s_ew[t][j];
                --j;
            }
            s_em[t][j + 1] = mi;
            s_ew[t][j + 1] = wi;
        }
    }
    __syncthreads();

    // ---- k-loop ----
    const int q = (w & 3) * 16 + l15;        // A row owned by this lane
    const int cw = w >> 2;                   // output-col half for this wave
    const int cnt = s_cnt[q];
    int ptr = 0;
    unsigned meta = (cnt > 0) ? s_em[q][0] : 0xffffffffu;

    const f4v zf = {0.0f, 0.0f, 0.0f, 0.0f};
    f4v acc[4]; acc[0] = zf; acc[1] = zf; acc[2] = zf; acc[3] = zf;
    float va[4][8];
    #pragma unroll
    for (int kk = 0; kk < 4; ++kk)
        #pragma unroll
        for (int j = 0; j < 8; ++j) va[kk][j] = 0.0f;
    AF af[4];
    #pragma unroll
    for (int kk = 0; kk < 4; ++kk) af[kk].u = (u4v){0u, 0u, 0u, 0u};

    for (int k = 0; k < K_P; ++k) {
        // issue this k's B-tile loads (linear, coalesced; consumed after barrier)
        const u4v* bsrc = ((const u4v*)Wtf) + (size_t)k * 2048 + t;
        const u4v b0 = bsrc[0], b1 = bsrc[512], b2 = bsrc[1024], b3 = bsrc[1536];

        // pointer-walk: process this lane's entries with key == k
        bool built = false;
        while (true) {
            const bool m = ((int)(meta >> 16) == k);
            if (!__any(m)) break;
            if (m) {
                const float wgt = s_ew[q][ptr];
                const float* fr = s_feats + (size_t)(meta & 0xffffu) * C_IN + quad * 8;
                #pragma unroll
                for (int kk = 0; kk < 4; ++kk) {
                    const fl4 f0 = *(const fl4*)(fr + kk * 32);
                    const fl4 f1 = *(const fl4*)(fr + kk * 32 + 4);
                    va[kk][0] = fmaf(wgt, f0.x, va[kk][0]);
                    va[kk][1] = fmaf(wgt, f0.y, va[kk][1]);
                    va[kk][2] = fmaf(wgt, f0.z, va[kk][2]);
                    va[kk][3] = fmaf(wgt, f0.w, va[kk][3]);
                    va[kk][4] = fmaf(wgt, f1.x, va[kk][4]);
                    va[kk][5] = fmaf(wgt, f1.y, va[kk][5]);
                    va[kk][6] = fmaf(wgt, f1.z, va[kk][6]);
                    va[kk][7] = fmaf(wgt, f1.w, va[kk][7]);
                }
                built = true;
                ++ptr;
                meta = (ptr < cnt) ? s_em[q][ptr] : 0xffffffffu;
            }
        }
        const unsigned long long anyb = __ballot(built);
        if (built) {
            #pragma unroll
            for (int kk = 0; kk < 4; ++kk) {
                af[kk].u[0] = pack_bf16(va[kk][0], va[kk][1]);
                af[kk].u[1] = pack_bf16(va[kk][2], va[kk][3]);
                af[kk].u[2] = pack_bf16(va[kk][4], va[kk][5]);
                af[kk].u[3] = pack_bf16(va[kk][6], va[kk][7]);
                #pragma unroll
                for (int j = 0; j < 8; ++j) va[kk][j] = 0.0f;
            }
        }

        // commit B tile to LDS (linear, conflict-free)
        {
            u4v* bdst = ((u4v*)s_B) + t;
            bdst[0] = b0; bdst[512] = b1; bdst[1024] = b2; bdst[1536] = b3;
        }
        __syncthreads();   // B ready

        if (anyb) {
            #pragma unroll
            for (int ct = 0; ct < 4; ++ct) {
                #pragma unroll
                for (int kk = 0; kk < 4; ++kk) {
                    const int slot = ((cw * 4 + ct) * 4 + kk) * 64 + lane;
                    const s8v b = *(const s8v*)(s_B + (size_t)slot * 8);
                    acc[ct] = __builtin_amdgcn_mfma_f32_16x16x32_bf16(af[kk].s, b, acc[ct], 0, 0, 0);
                }
            }
        }
        if (built) {
            #pragma unroll
            for (int kk = 0; kk < 4; ++kk) af[kk].u = (u4v){0u, 0u, 0u, 0u};
        }
        __syncthreads();   // protect s_B until all reads done
    }

    // ---- epilogue: C/D layout col=lane&15, row=quad*4+reg ----
    #pragma unroll
    for (int ct = 0; ct < 4; ++ct) {
        #pragma unroll
        for (int r = 0; r < 4; ++r) {
            const int qg = qbase + (w & 3) * 16 + quad * 4 + r;
            if (qg < M_Q)
                out[(size_t)qg * C_OUT + cw * 64 + ct * 16 + l15] = acc[ct][r];
        }
    }
}

extern "C" void kernel_launch(void* const* d_in, const int* in_sizes, int n_in,
                              void* d_out, int out_size, void* d_ws, size_t ws_size,
                              hipStream_t stream) {
    const float* q_pts         = (const float*)d_in[0];
    const float* s_pts         = (const float*)d_in[1];
    const float* s_feats       = (const float*)d_in[2];
    const float* kernel_points = (const float*)d_in[4];
    const float* weights       = (const float*)d_in[5];
    float* out = (float*)d_out;
    const bool i64 = (in_sizes[3] == 2 * M_Q * H_N);

    unsigned short* Wtf = (unsigned short*)d_ws;
    const int slots = K_P * 2 * 4 * 4 * 64;
    wcvt_frag<<<(slots + 255) / 256, 256, 0, stream>>>(weights, Wtf);

    dim3 grid((M_Q + QB - 1) / QB), block(NT);
    if (i64)
        kpconv_v6<long long><<<grid, block, 0, stream>>>(
            q_pts, s_pts, s_feats, (const long long*)d_in[3], kernel_points, Wtf, out);
    else
        kpconv_v6<int><<<grid, block, 0, stream>>>(
            q_pts, s_pts, s_feats, (const int*)d_in[3], kernel_points, Wtf, out);
}